// Round 6
// baseline (276.656 us; speedup 1.0000x reference)
//
#include <hip/hip_runtime.h>

#define BATCH 16
#define CH 256
#define HW (128 * 128)     // 16384 elements per channel
#define KSEL 16
#define GSPLIT_LOG 1
#define GSPLIT (1 << GSPLIT_LOG)          // 2 blocks per (b,k) copy
#define NGATHER (BATCH * KSEL * GSPLIT)   // 512 gather blocks
#define NBLOCKS (BATCH * CH)              // 4096 blocks

// One fused kernel:
//  phase A (all 4096 blocks): mean of own channel -> publish w + done[b]++
//  phase B (the 256th publisher of each batch): compute idx row once
//  phase C (last 512 blocks): wait idxdone[b], copy a 32 KiB slice
// Deadlock-free: every block publishes its mean BEFORE any wait, and
// waiters (512) < resident blocks (>=1024), so remaining means always drain.
__global__ __launch_bounds__(256) void fused_kernel(const float* __restrict__ x,
                                                    float* __restrict__ w,
                                                    int* __restrict__ idx,
                                                    int* __restrict__ done,
                                                    int* __restrict__ idxdone,
                                                    float* __restrict__ out) {
    const int bc    = blockIdx.x;          // 0 .. 4095 (== global channel id)
    const int b_own = bc >> 8;             // batch of my channel
    const int t     = threadIdx.x;         // 0 .. 255

    // ---- phase A: mean of own channel --------------------------------
    const float4* p = reinterpret_cast<const float4*>(x + (size_t)bc * HW);
    float s = 0.0f;
    #pragma unroll
    for (int i = 0; i < HW / 4 / 256; ++i) {
        float4 v = p[t + i * 256];
        s += (v.x + v.y) + (v.z + v.w);
    }
    #pragma unroll
    for (int off = 32; off > 0; off >>= 1)
        s += __shfl_down(s, off, 64);

    __shared__ float partial[4];
    __shared__ int   flag;                 // am I the last publisher of my batch?
    if ((t & 63) == 0) partial[t >> 6] = s;
    if (t == 0) flag = 0;
    __syncthreads();
    if (t == 0) {
        float tot = (partial[0] + partial[1]) + (partial[2] + partial[3]);
        __hip_atomic_store(&w[bc], tot * (1.0f / (float)HW),
                           __ATOMIC_RELAXED, __HIP_MEMORY_SCOPE_AGENT);
        int old = __hip_atomic_fetch_add(&done[b_own], 1,
                                         __ATOMIC_ACQ_REL, __HIP_MEMORY_SCOPE_AGENT);
        if (old == CH - 1) flag = 1;
    }
    __syncthreads();

    // ---- phase B: last publisher computes idx row (once per batch) ----
    __shared__ float sw[CH];
    if (flag) {
        sw[t] = __hip_atomic_load(&w[b_own * CH + t],
                                  __ATOMIC_RELAXED, __HIP_MEMORY_SCOPE_AGENT);
        __syncthreads();
        const float mine = sw[t];
        const float4* sw4 = reinterpret_cast<const float4*>(sw);
        int rank = 0;
        #pragma unroll 8
        for (int j4 = 0; j4 < CH / 4; ++j4) {
            float4 v = sw4[j4];
            const int j = j4 * 4;
            rank += (v.x < mine) || (v.x == mine && (j + 0) < t);
            rank += (v.y < mine) || (v.y == mine && (j + 1) < t);
            rank += (v.z < mine) || (v.z == mine && (j + 2) < t);
            rank += (v.w < mine) || (v.w == mine && (j + 3) < t);
        }
        if (rank < KSEL)
            __hip_atomic_store(&idx[b_own * KSEL + rank], t,
                               __ATOMIC_RELAXED, __HIP_MEMORY_SCOPE_AGENT);
        __syncthreads();                  // all idx stores done
        if (t == 0)
            __hip_atomic_store(&idxdone[b_own], 1,
                               __ATOMIC_RELEASE, __HIP_MEMORY_SCOPE_AGENT);
    }

    // ---- phase C: gather (last NGATHER blocks only) -------------------
    if (bc >= NBLOCKS - NGATHER) {
        const int g    = bc - (NBLOCKS - NGATHER);
        const int part = g & (GSPLIT - 1);
        const int bk   = g >> GSPLIT_LOG;  // 0 .. BATCH*KSEL-1
        const int b    = bk >> 4;
        __shared__ int sel;
        if (t == 0) {
            while (__hip_atomic_load(&idxdone[b],
                                     __ATOMIC_ACQUIRE, __HIP_MEMORY_SCOPE_AGENT) == 0)
                __builtin_amdgcn_s_sleep(2);
            sel = __hip_atomic_load(&idx[bk],
                                    __ATOMIC_RELAXED, __HIP_MEMORY_SCOPE_AGENT);
        }
        __syncthreads();
        const int c = sel;

        const int slice = HW / GSPLIT;     // 8192 floats = 32 KiB
        const float4* src = reinterpret_cast<const float4*>(
            x + ((size_t)b * CH + c) * HW + (size_t)part * slice);
        float4* dst = reinterpret_cast<float4*>(
            out + (size_t)bk * HW + (size_t)part * slice);

        #pragma unroll
        for (int i = 0; i < slice / 4 / 256; ++i)   // 8 float4 per thread
            dst[t + i * 256] = src[t + i * 256];
    }
}

extern "C" void kernel_launch(void* const* d_in, const int* in_sizes, int n_in,
                              void* d_out, int out_size, void* d_ws, size_t ws_size,
                              hipStream_t stream) {
    const float* x = (const float*)d_in[0];
    float* out = (float*)d_out;

    // ws layout: w[4096] f32 | idx[256] i32 | done[16] i32 | idxdone[16] i32
    float* w       = (float*)d_ws;
    int*   idx     = (int*)((char*)d_ws + NBLOCKS * sizeof(float));
    int*   done    = idx + BATCH * KSEL;
    int*   idxdone = done + BATCH;

    // re-zero the flags every call (graph replays reuse ws)
    hipMemsetAsync(done, 0, 2 * BATCH * sizeof(int), stream);

    fused_kernel<<<NBLOCKS, 256, 0, stream>>>(x, w, idx, done, idxdone, out);
}

// Round 8
// 61.489 us; speedup vs baseline: 4.4993x; 4.4993x over previous
//
#include <hip/hip_runtime.h>

#define BATCH 16
#define CH 256
#define HW (128 * 128)   // 16384 elements per channel
#define KSEL 16

typedef float floatx4 __attribute__((ext_vector_type(4)));  // native vec for nt-load

// ---- Kernel 1: per-(b,c) mean over H*W (nontemporal streaming reads) -----
__global__ __launch_bounds__(256) void mean_kernel(const float* __restrict__ x,
                                                   float* __restrict__ w) {
    const int bc = blockIdx.x;                       // 0 .. BATCH*CH-1
    const int t  = threadIdx.x;                      // 0 .. 255
    const floatx4* p = reinterpret_cast<const floatx4*>(x + (size_t)bc * HW);

    float s = 0.0f;
    #pragma unroll
    for (int i = 0; i < HW / 4 / 256; ++i) {         // 16 float4 per thread
        floatx4 v = __builtin_nontemporal_load(&p[t + i * 256]);
        s += (v.x + v.y) + (v.z + v.w);
    }
    // wave (64-lane) shuffle reduce
    #pragma unroll
    for (int off = 32; off > 0; off >>= 1)
        s += __shfl_down(s, off, 64);

    __shared__ float partial[4];
    const int wave = t >> 6;
    const int lane = t & 63;
    if (lane == 0) partial[wave] = s;
    __syncthreads();
    if (t == 0) {
        float tot = (partial[0] + partial[1]) + (partial[2] + partial[3]);
        w[bc] = tot * (1.0f / (float)HW);
    }
}

// ---- Kernel 2 (fused): float4-vectorized rank + full-channel gather ------
// One block per (b,k) output channel (SPLIT=1 — proven optimal in R2-R5).
// 256 threads load w[b][:] into LDS; thread c computes the stable-ascending
// rank of channel c via 64 ds_read_b128 broadcasts; the thread whose
// rank == k publishes its channel; block copies the 64 KiB channel.
__global__ __launch_bounds__(256) void rank_gather_kernel(const float* __restrict__ x,
                                                          const float* __restrict__ w,
                                                          float* __restrict__ out) {
    const int bk = blockIdx.x;                       // 0 .. BATCH*KSEL-1
    const int b  = bk >> 4;
    const int k  = bk & (KSEL - 1);
    const int t  = threadIdx.x;                      // 0 .. 255 (== channel id)

    __shared__ float sw[CH];
    __shared__ int   sel;
    sw[t] = w[b * CH + t];
    __syncthreads();

    const float mine = sw[t];
    const float4* sw4 = reinterpret_cast<const float4*>(sw);
    int rank = 0;
    #pragma unroll 8
    for (int j4 = 0; j4 < CH / 4; ++j4) {            // 64 broadcast b128 reads
        float4 v = sw4[j4];
        const int j = j4 * 4;
        rank += (v.x < mine) || (v.x == mine && (j + 0) < t);
        rank += (v.y < mine) || (v.y == mine && (j + 1) < t);
        rank += (v.z < mine) || (v.z == mine && (j + 2) < t);
        rank += (v.w < mine) || (v.w == mine && (j + 3) < t);
    }
    if (rank == k) sel = t;                          // exactly one thread matches
    __syncthreads();
    const int c = sel;

    const float4* src = reinterpret_cast<const float4*>(x + ((size_t)b * CH + c) * HW);
    float4* dst       = reinterpret_cast<float4*>(out + (size_t)bk * HW);

    #pragma unroll
    for (int i = 0; i < HW / 4 / 256; ++i)           // 16 float4 per thread
        dst[t + i * 256] = src[t + i * 256];
}

extern "C" void kernel_launch(void* const* d_in, const int* in_sizes, int n_in,
                              void* d_out, int out_size, void* d_ws, size_t ws_size,
                              hipStream_t stream) {
    const float* x = (const float*)d_in[0];
    float* out = (float*)d_out;

    float* w = (float*)d_ws;                         // BATCH*CH floats

    mean_kernel<<<BATCH * CH, 256, 0, stream>>>(x, w);
    rank_gather_kernel<<<BATCH * KSEL, 256, 0, stream>>>(x, w, out);
}

// Round 9
// 60.124 us; speedup vs baseline: 4.6014x; 1.0227x over previous
//
#include <hip/hip_runtime.h>

#define BATCH 16
#define CH 256
#define HW (128 * 128)   // 16384 elements per channel
#define KSEL 16
#define SPLIT_LOG 2
#define SPLIT (1 << SPLIT_LOG)   // 4 blocks per (b,k) channel copy

// ---- Kernel 1: per-(b,c) mean over H*W (exact R2 winner) -----------------
__global__ __launch_bounds__(256) void mean_kernel(const float* __restrict__ x,
                                                   float* __restrict__ w) {
    const int bc = blockIdx.x;                       // 0 .. BATCH*CH-1
    const int t  = threadIdx.x;                      // 0 .. 255
    const float4* p = reinterpret_cast<const float4*>(x + (size_t)bc * HW);

    float s = 0.0f;
    #pragma unroll
    for (int i = 0; i < HW / 4 / 256; ++i) {         // 16 float4 per thread
        float4 v = p[t + i * 256];
        s += (v.x + v.y) + (v.z + v.w);
    }
    // wave (64-lane) shuffle reduce
    #pragma unroll
    for (int off = 32; off > 0; off >>= 1)
        s += __shfl_down(s, off, 64);

    __shared__ float partial[4];
    const int wave = t >> 6;
    const int lane = t & 63;
    if (lane == 0) partial[wave] = s;
    __syncthreads();
    if (t == 0) {
        float tot = (partial[0] + partial[1]) + (partial[2] + partial[3]);
        w[bc] = tot * (1.0f / (float)HW);
    }
}

// ---- Kernel 2 (fused): SMEM-path rank + split channel gather -------------
// Block g = bk*SPLIT + part. Thread t loads its own w (coalesced); the rank
// scan reads w[b][:] via WAVE-UNIFORM addresses -> s_load_dwordx4 (scalar
// cache), so there is NO LDS staging chain and NO pre-rank barrier — the
// mechanism that made SPLIT>1 lose in R3/R5 is gone. Only a 4-byte LDS
// broadcast of the selected channel remains.
__global__ __launch_bounds__(256) void rank_gather_kernel(const float* __restrict__ x,
                                                          const float* __restrict__ w,
                                                          float* __restrict__ out) {
    const int g    = blockIdx.x;
    const int part = g & (SPLIT - 1);
    const int bk   = g >> SPLIT_LOG;                 // 0 .. BATCH*KSEL-1
    const int b    = bk >> 4;
    const int k    = bk & (KSEL - 1);
    const int t    = threadIdx.x;                    // 0 .. 255 (== channel id)

    const float mine = w[b * CH + t];                // coalesced per-lane load
    const float4* wrow = reinterpret_cast<const float4*>(w + b * CH);

    int rank = 0;
    #pragma unroll 8
    for (int j4 = 0; j4 < CH / 4; ++j4) {            // uniform addr -> s_load
        float4 v = wrow[j4];
        const int j = j4 * 4;
        rank += (v.x < mine) || (v.x == mine && (j + 0) < t);
        rank += (v.y < mine) || (v.y == mine && (j + 1) < t);
        rank += (v.z < mine) || (v.z == mine && (j + 2) < t);
        rank += (v.w < mine) || (v.w == mine && (j + 3) < t);
    }

    __shared__ int sel;
    if (rank == k) sel = t;                          // exactly one thread matches
    __syncthreads();
    const int c = sel;

    const int slice = HW / SPLIT;                    // 4096 floats = 16 KiB
    const float4* src = reinterpret_cast<const float4*>(
        x + ((size_t)b * CH + c) * HW + (size_t)part * slice);
    float4* dst = reinterpret_cast<float4*>(
        out + (size_t)bk * HW + (size_t)part * slice);

    #pragma unroll
    for (int i = 0; i < slice / 4 / 256; ++i)        // 4 float4 per thread
        dst[t + i * 256] = src[t + i * 256];
}

extern "C" void kernel_launch(void* const* d_in, const int* in_sizes, int n_in,
                              void* d_out, int out_size, void* d_ws, size_t ws_size,
                              hipStream_t stream) {
    const float* x = (const float*)d_in[0];
    float* out = (float*)d_out;

    float* w = (float*)d_ws;                         // BATCH*CH floats

    mean_kernel<<<BATCH * CH, 256, 0, stream>>>(x, w);
    rank_gather_kernel<<<BATCH * KSEL * SPLIT, 256, 0, stream>>>(x, w, out);
}

// Round 10
// 56.205 us; speedup vs baseline: 4.9222x; 1.0697x over previous
//
#include <hip/hip_runtime.h>

#define BATCH 16
#define CH 256
#define HW (128 * 128)   // 16384 elements per channel
#define KSEL 16

typedef float floatx4 __attribute__((ext_vector_type(4)));  // native vec for nt builtins

// ---- Kernel 1: per-(b,c) mean over H*W (exact R2 winner — do not touch) --
__global__ __launch_bounds__(256) void mean_kernel(const float* __restrict__ x,
                                                   float* __restrict__ w) {
    const int bc = blockIdx.x;                       // 0 .. BATCH*CH-1
    const int t  = threadIdx.x;                      // 0 .. 255
    const float4* p = reinterpret_cast<const float4*>(x + (size_t)bc * HW);

    float s = 0.0f;
    #pragma unroll
    for (int i = 0; i < HW / 4 / 256; ++i) {         // 16 float4 per thread
        float4 v = p[t + i * 256];
        s += (v.x + v.y) + (v.z + v.w);
    }
    // wave (64-lane) shuffle reduce
    #pragma unroll
    for (int off = 32; off > 0; off >>= 1)
        s += __shfl_down(s, off, 64);

    __shared__ float partial[4];
    const int wave = t >> 6;
    const int lane = t & 63;
    if (lane == 0) partial[wave] = s;
    __syncthreads();
    if (t == 0) {
        float tot = (partial[0] + partial[1]) + (partial[2] + partial[3]);
        w[bc] = tot * (1.0f / (float)HW);
    }
}

// ---- Kernel 2 (fused, R2 structure): scalar LDS rank + full-channel copy --
// One block per (b,k). Only change vs R2: nontemporal stores on the output
// copy — out is never re-read, so don't let it evict x from L2/L3 while the
// gather is still reading x.
__global__ __launch_bounds__(256) void rank_gather_kernel(const float* __restrict__ x,
                                                          const float* __restrict__ w,
                                                          float* __restrict__ out) {
    const int bk = blockIdx.x;                       // 0 .. BATCH*KSEL-1
    const int b  = bk >> 4;
    const int k  = bk & (KSEL - 1);
    const int t  = threadIdx.x;                      // 0 .. 255 (== channel id)

    __shared__ float sw[CH];
    __shared__ int   sel;
    sw[t] = w[b * CH + t];
    __syncthreads();

    const float mine = sw[t];
    int rank = 0;
    #pragma unroll 8
    for (int j = 0; j < CH; ++j) {
        float v = sw[j];
        rank += (v < mine) || (v == mine && j < t);  // stable tie-break
    }
    if (rank == k) sel = t;                          // exactly one thread matches
    __syncthreads();
    const int c = sel;

    const floatx4* src = reinterpret_cast<const floatx4*>(x + ((size_t)b * CH + c) * HW);
    floatx4* dst       = reinterpret_cast<floatx4*>(out + (size_t)bk * HW);

    #pragma unroll
    for (int i = 0; i < HW / 4 / 256; ++i) {         // 16 float4 per thread
        floatx4 v = src[t + i * 256];
        __builtin_nontemporal_store(v, &dst[t + i * 256]);
    }
}

extern "C" void kernel_launch(void* const* d_in, const int* in_sizes, int n_in,
                              void* d_out, int out_size, void* d_ws, size_t ws_size,
                              hipStream_t stream) {
    const float* x = (const float*)d_in[0];
    float* out = (float*)d_out;

    float* w = (float*)d_ws;                         // BATCH*CH floats

    mean_kernel<<<BATCH * CH, 256, 0, stream>>>(x, w);
    rank_gather_kernel<<<BATCH * KSEL, 256, 0, stream>>>(x, w, out);
}